// Round 7
// baseline (333.568 us; speedup 1.0000x reference)
//
#include <hip/hip_runtime.h>
#include <cstdint>
#include <cstddef>

#define B_ 16
#define E_ 1024
#define N_ 1024
#define H_ 128
#define CAP 256   // max nonzeros per row/col; Bernoulli(0.1,1024): mean 102, std 9.6
#define NC 16     // e-chunks for column build
#define EC 64     // E_/NC

typedef unsigned short u16;

__device__ __forceinline__ float wave_sum64(float v) {
    v += __shfl_xor(v, 32);
    v += __shfl_xor(v, 16);
    v += __shfl_xor(v, 8);
    v += __shfl_xor(v, 4);
    v += __shfl_xor(v, 2);
    v += __shfl_xor(v, 1);
    return v;
}

// Row nonzero lists: one block per (b,e). Coalesced, ordered (ascending n).
__global__ void build_rows(const float* __restrict__ adj,
                           u16* __restrict__ idx, int* __restrict__ cnt_out) {
    int be = blockIdx.x;                      // b*E + e
    const float* row = adj + (size_t)be * N_;
    __shared__ int wcnt[4];
    __shared__ int base;
    int tid = threadIdx.x, lane = tid & 63, wv = tid >> 6;
    if (tid == 0) base = 0;
    __syncthreads();
    for (int c0 = 0; c0 < N_; c0 += 256) {
        float v = row[c0 + tid];
        unsigned long long m = __ballot(v != 0.0f);
        if (lane == 0) wcnt[wv] = __popcll(m);
        __syncthreads();
        int pos = base;
        for (int w = 0; w < wv; ++w) pos += wcnt[w];
        pos += __popcll(m & ((1ull << lane) - 1ull));
        if (v != 0.0f && pos < CAP)
            idx[(size_t)be * CAP + pos] = (u16)(c0 + tid);
        __syncthreads();
        if (tid == 0) base += wcnt[0] + wcnt[1] + wcnt[2] + wcnt[3];
        __syncthreads();
    }
    if (tid == 0) cnt_out[be] = base < CAP ? base : CAP;
}

// --- Column lists, 3-phase parallel, deterministic (ascending e) ---
__global__ void col_count(const float* __restrict__ adj, int* __restrict__ cnt_chunk) {
    int blk = blockIdx.x;
    int ng = blk & 3;                 // n-group
    int c  = (blk >> 2) & (NC - 1);   // e-chunk
    int b  = blk >> 6;
    int n = (ng << 8) + threadIdx.x;
    const float* base = adj + ((size_t)(b * E_ + c * EC)) * N_ + n;
    int cc = 0;
#pragma unroll 8
    for (int e = 0; e < EC; ++e)
        cc += (base[(size_t)e * N_] != 0.0f);
    cnt_chunk[(size_t)(b * NC + c) * N_ + n] = cc;
}

__global__ void col_prefix(const int* __restrict__ cnt_chunk,
                           int* __restrict__ off_chunk, int* __restrict__ cnt_out) {
    int idx = blockIdx.x * 256 + threadIdx.x;   // b*N + n
    int b = idx >> 10, n = idx & 1023;
    int run = 0;
    for (int c = 0; c < NC; ++c) {
        size_t p = (size_t)(b * NC + c) * N_ + n;
        off_chunk[p] = run;
        run += cnt_chunk[p];
    }
    cnt_out[idx] = run < CAP ? run : CAP;
}

__global__ void col_place(const float* __restrict__ adj,
                          const int* __restrict__ off_chunk, u16* __restrict__ idx) {
    int blk = blockIdx.x;
    int ng = blk & 3;
    int c  = (blk >> 2) & (NC - 1);
    int b  = blk >> 6;
    int n = (ng << 8) + threadIdx.x;
    const float* base = adj + ((size_t)(b * E_ + c * EC)) * N_ + n;
    int pos = off_chunk[(size_t)(b * NC + c) * N_ + n];
    u16* lst = idx + ((size_t)b * N_ + n) * CAP;
    for (int e = 0; e < EC; ++e) {
        if (base[(size_t)e * N_] != 0.0f) {
            if (pos < CAP) lst[pos] = (u16)(c * EC + e);
            ++pos;
        }
    }
}

// edge_init[b,e,:] = mean of incident node rows. 256 thr, float4, 8 slices.
__global__ void edge_init(const float* __restrict__ nodes,
                          const u16* __restrict__ ridx, const int* __restrict__ rcnt,
                          float* __restrict__ edge) {
    int be = blockIdx.x;
    int b = be >> 10;
    int tid = threadIdx.x, d4 = tid & 31, h = tid >> 5;
    __shared__ u16 sidx[CAP];
    __shared__ float4 part4[256];
    int cnt = rcnt[be];
    for (int i = tid; i < cnt; i += 256) sidx[i] = ridx[(size_t)be * CAP + i];
    __syncthreads();
    const float4* nb4 = (const float4*)(nodes + (size_t)b * N_ * H_);
    float4 acc = make_float4(0.f, 0.f, 0.f, 0.f);
    for (int i = h; i < cnt; i += 8) {
        float4 v = nb4[((unsigned)sidx[i] << 5) + d4];
        acc.x += v.x; acc.y += v.y; acc.z += v.z; acc.w += v.w;
    }
    part4[tid] = acc;
    __syncthreads();
    if (tid < 32) {
        float4 r = make_float4(0.f, 0.f, 0.f, 0.f);
#pragma unroll
        for (int k = 0; k < 8; ++k) {
            float4 p = part4[tid + (k << 5)];
            r.x += p.x; r.y += p.y; r.z += p.z; r.w += p.w;
        }
        float inv = 1.0f / (float)(cnt > 0 ? cnt : 1);
        r.x *= inv; r.y *= inv; r.z *= inv; r.w *= inv;
        ((float4*)edge)[(size_t)be * 32 + tid] = r;
    }
}

// Single-touch fused masked-softmax attention over a nonzero list.
// Row loaded ONCE (8 lanes x 4 float4 = 512 B in regs): dot -> 3-shfl ->
// leaky -> exp (no max shift, r5-validated) -> acc += ww * row in registers.
// 2x unrolled main loop: two independent load/dot/shfl chains per iteration
// to hide the ~100-cycle dependent-shfl latency.
// Merge buffer transposed to [4][256] (16 B thread stride -> conflict-free;
// the [256][4] layout was a 32-way write conflict, 6.3M conflict-cycles).
// Denominator: every lane adds ww (8x overcount, /8 at end).
// Safe for qsrc == out (block reads only its own q row, writes only its row).
// XCD swizzle: batch b on XCD b%8 -> per-XCD kv footprint 1 MB (L2-resident).
__global__ void attn_gather(const float* __restrict__ qsrc,
                            const float* __restrict__ kv,
                            const float* __restrict__ w,
                            const u16* __restrict__ lidx, const int* __restrict__ lcnt,
                            float* __restrict__ out) {
    int x = blockIdx.x;
    int xcd = x & 7;
    int jb = x >> 3;                     // 0..2047
    int b = xcd + ((jb >> 10) << 3);     // batches {xcd, xcd+8}
    int rrow = jb & 1023;
    int br = (b << 10) + rrow;
    int tid = threadIdx.x, lane = tid & 63, wv = tid >> 6;   // 256 threads
    __shared__ float qsh[H_];
    __shared__ u16 sidx[CAP];
    __shared__ float4 sacc[4][256];      // [kb][thread] -> conflict-free b128
    __shared__ float dnw[4];
    int cnt = lcnt[br];
    for (int i = tid; i < cnt; i += 256) sidx[i] = lidx[(size_t)br * CAP + i];
    if (tid < H_) qsh[tid] = qsrc[(size_t)br * H_ + tid] * w[tid];
    __syncthreads();
    float wb = w[H_];
    const float4* kvb4 = (const float4*)(kv + (size_t)b * 1024 * H_);

    int esub = lane >> 3, dsub = lane & 7;   // entry-in-wave, d-slice
    float4 qr0 = ((const float4*)qsh)[dsub];
    float4 qr1 = ((const float4*)qsh)[8 + dsub];
    float4 qr2 = ((const float4*)qsh)[16 + dsub];
    float4 qr3 = ((const float4*)qsh)[24 + dsub];
    float4 a0 = make_float4(0.f, 0.f, 0.f, 0.f);
    float4 a1 = a0, a2 = a0, a3 = a0;
    float dpart = 0.f;
    int ibase = (wv << 3) + esub;

    for (int i0 = 0; i0 < cnt; i0 += 64) {
        int iA = i0 + ibase;
        int iB = iA + 32;
        unsigned roA = (unsigned)((iA < cnt) ? sidx[iA] : 0) << 5;
        unsigned roB = (unsigned)((iB < cnt) ? sidx[iB] : 0) << 5;
        // issue all 8 loads up front (independent)
        float4 kA0 = kvb4[roA + dsub];
        float4 kA1 = kvb4[roA + 8 + dsub];
        float4 kA2 = kvb4[roA + 16 + dsub];
        float4 kA3 = kvb4[roA + 24 + dsub];
        float4 kB0 = kvb4[roB + dsub];
        float4 kB1 = kvb4[roB + 8 + dsub];
        float4 kB2 = kvb4[roB + 16 + dsub];
        float4 kB3 = kvb4[roB + 24 + dsub];
        // two independent dot chains
        float dA0 = 0.f, dA1 = 0.f, dB0 = 0.f, dB1 = 0.f;
        dA0 = fmaf(kA0.x, qr0.x, dA0); dA0 = fmaf(kA0.y, qr0.y, dA0);
        dA0 = fmaf(kA0.z, qr0.z, dA0); dA0 = fmaf(kA0.w, qr0.w, dA0);
        dB0 = fmaf(kB0.x, qr0.x, dB0); dB0 = fmaf(kB0.y, qr0.y, dB0);
        dB0 = fmaf(kB0.z, qr0.z, dB0); dB0 = fmaf(kB0.w, qr0.w, dB0);
        dA1 = fmaf(kA1.x, qr1.x, dA1); dA1 = fmaf(kA1.y, qr1.y, dA1);
        dA1 = fmaf(kA1.z, qr1.z, dA1); dA1 = fmaf(kA1.w, qr1.w, dA1);
        dB1 = fmaf(kB1.x, qr1.x, dB1); dB1 = fmaf(kB1.y, qr1.y, dB1);
        dB1 = fmaf(kB1.z, qr1.z, dB1); dB1 = fmaf(kB1.w, qr1.w, dB1);
        dA0 = fmaf(kA2.x, qr2.x, dA0); dA0 = fmaf(kA2.y, qr2.y, dA0);
        dA0 = fmaf(kA2.z, qr2.z, dA0); dA0 = fmaf(kA2.w, qr2.w, dA0);
        dB0 = fmaf(kB2.x, qr2.x, dB0); dB0 = fmaf(kB2.y, qr2.y, dB0);
        dB0 = fmaf(kB2.z, qr2.z, dB0); dB0 = fmaf(kB2.w, qr2.w, dB0);
        dA1 = fmaf(kA3.x, qr3.x, dA1); dA1 = fmaf(kA3.y, qr3.y, dA1);
        dA1 = fmaf(kA3.z, qr3.z, dA1); dA1 = fmaf(kA3.w, qr3.w, dA1);
        dB1 = fmaf(kB3.x, qr3.x, dB1); dB1 = fmaf(kB3.y, qr3.y, dB1);
        dB1 = fmaf(kB3.z, qr3.z, dB1); dB1 = fmaf(kB3.w, qr3.w, dB1);
        float dA = dA0 + dA1, dB = dB0 + dB1;
        // interleaved (independent) shfl chains
        dA += __shfl_xor(dA, 1);  dB += __shfl_xor(dB, 1);
        dA += __shfl_xor(dA, 2);  dB += __shfl_xor(dB, 2);
        dA += __shfl_xor(dA, 4);  dB += __shfl_xor(dB, 4);
        float pA = dA + wb, pB = dB + wb;
        pA = pA >= 0.f ? pA : 0.2f * pA;  // LeakyReLU(0.2)
        pB = pB >= 0.f ? pB : 0.2f * pB;
        float wA = (iA < cnt) ? __expf(pA) : 0.f;
        float wB = (iB < cnt) ? __expf(pB) : 0.f;
        dpart += wA + wB;
        a0.x = fmaf(wA, kA0.x, a0.x); a0.y = fmaf(wA, kA0.y, a0.y);
        a0.z = fmaf(wA, kA0.z, a0.z); a0.w = fmaf(wA, kA0.w, a0.w);
        a1.x = fmaf(wA, kA1.x, a1.x); a1.y = fmaf(wA, kA1.y, a1.y);
        a1.z = fmaf(wA, kA1.z, a1.z); a1.w = fmaf(wA, kA1.w, a1.w);
        a2.x = fmaf(wA, kA2.x, a2.x); a2.y = fmaf(wA, kA2.y, a2.y);
        a2.z = fmaf(wA, kA2.z, a2.z); a2.w = fmaf(wA, kA2.w, a2.w);
        a3.x = fmaf(wA, kA3.x, a3.x); a3.y = fmaf(wA, kA3.y, a3.y);
        a3.z = fmaf(wA, kA3.z, a3.z); a3.w = fmaf(wA, kA3.w, a3.w);
        a0.x = fmaf(wB, kB0.x, a0.x); a0.y = fmaf(wB, kB0.y, a0.y);
        a0.z = fmaf(wB, kB0.z, a0.z); a0.w = fmaf(wB, kB0.w, a0.w);
        a1.x = fmaf(wB, kB1.x, a1.x); a1.y = fmaf(wB, kB1.y, a1.y);
        a1.z = fmaf(wB, kB1.z, a1.z); a1.w = fmaf(wB, kB1.w, a1.w);
        a2.x = fmaf(wB, kB2.x, a2.x); a2.y = fmaf(wB, kB2.y, a2.y);
        a2.z = fmaf(wB, kB2.z, a2.z); a2.w = fmaf(wB, kB2.w, a2.w);
        a3.x = fmaf(wB, kB3.x, a3.x); a3.y = fmaf(wB, kB3.y, a3.y);
        a3.z = fmaf(wB, kB3.z, a3.z); a3.w = fmaf(wB, kB3.w, a3.w);
    }

    // per-wave denom (each entry counted by its 8 lanes -> /8 at the end)
    dpart = wave_sum64(dpart);
    if (lane == 0) dnw[wv] = dpart;
    sacc[0][tid] = a0; sacc[1][tid] = a1; sacc[2][tid] = a2; sacc[3][tid] = a3;
    __syncthreads();

    // merge: output float4 slot j = kb*8 + ds (dims 4j..4j+3); contributors
    // are threads wv2*64 + es*8 + ds (reg kb), wv2 in 0..3, es in 0..7.
    if (tid < 32) {
        int kb = tid >> 3, ds = tid & 7;
        float4 rr = make_float4(0.f, 0.f, 0.f, 0.f);
#pragma unroll
        for (int wv2 = 0; wv2 < 4; ++wv2)
#pragma unroll
            for (int es = 0; es < 8; ++es) {
                float4 p = sacc[kb][(wv2 << 6) + (es << 3) + ds];
                rr.x += p.x; rr.y += p.y; rr.z += p.z; rr.w += p.w;
            }
        float denom = (dnw[0] + dnw[1] + dnw[2] + dnw[3]) * 0.125f;
        float rden = denom > 0.f ? 1.0f / denom : 0.f;
        rr.x *= rden; rr.y *= rden; rr.z *= rden; rr.w *= rden;
        ((float4*)out)[(size_t)br * 32 + (kb << 3) + ds] = rr;
    }
}

extern "C" void kernel_launch(void* const* d_in, const int* in_sizes, int n_in,
                              void* d_out, int out_size, void* d_ws, size_t ws_size,
                              hipStream_t stream) {
    const float* nodes_in = (const float*)d_in[0];   // (B,N,H) f32
    const float* adj      = (const float*)d_in[1];   // (B,E,N) f32, binary
    const float* w1       = (const float*)d_in[2];   // (H+1)
    const float* w2       = (const float*)d_in[3];   // (H+1)

    char* ws = (char*)d_ws;
    size_t off = 0;
    u16* row_idx = (u16*)(ws + off); off += (size_t)B_ * E_ * CAP * sizeof(u16);
    u16* col_idx = (u16*)(ws + off); off += (size_t)B_ * N_ * CAP * sizeof(u16);
    int* row_cnt = (int*)(ws + off); off += (size_t)B_ * E_ * sizeof(int);
    int* col_cnt = (int*)(ws + off); off += (size_t)B_ * N_ * sizeof(int);
    int* cnt_chunk = (int*)(ws + off); off += (size_t)B_ * NC * N_ * sizeof(int);
    int* off_chunk = (int*)(ws + off); off += (size_t)B_ * NC * N_ * sizeof(int);

    float* out_nodes = (float*)d_out;                       // (B,N,H)
    float* out_edge  = out_nodes + (size_t)B_ * N_ * H_;    // (B,E,H)

    build_rows<<<dim3(B_ * E_), dim3(256), 0, stream>>>(adj, row_idx, row_cnt);
    col_count <<<dim3(B_ * NC * 4), dim3(256), 0, stream>>>(adj, cnt_chunk);
    col_prefix<<<dim3(B_ * N_ / 256), dim3(256), 0, stream>>>(cnt_chunk, off_chunk, col_cnt);
    col_place <<<dim3(B_ * NC * 4), dim3(256), 0, stream>>>(adj, off_chunk, col_idx);
    edge_init <<<dim3(B_ * E_), dim3(256), 0, stream>>>(nodes_in, row_idx, row_cnt, out_edge);

    const float* ncur = nodes_in;
    for (int s = 0; s < 2; ++s) {
        attn_gather<<<dim3(B_ * E_), dim3(256), 0, stream>>>(
            out_edge, ncur, w1, row_idx, row_cnt, out_edge);
        attn_gather<<<dim3(B_ * N_), dim3(256), 0, stream>>>(
            ncur, out_edge, w2, col_idx, col_cnt, out_nodes);
        ncur = out_nodes;
    }
}